// Round 15
// baseline (117.088 us; speedup 1.0000x reference)
//
#include <hip/hip_runtime.h>
#include <cstdint>
#include <cstddef>

#define N_ROWS 16384   // B*T
#define KCODES 4096
#define DIM    256

// -------- kernel 1: codebook inverse norms --------
__global__ __launch_bounds__(256) void cinv_kernel(
    const float* __restrict__ cb, float* __restrict__ cinv)
{
    int r    = blockIdx.x * 4 + (threadIdx.x >> 6);   // one wave per codebook row
    int lane = threadIdx.x & 63;
    float4 v = reinterpret_cast<const float4*>(cb + (size_t)r * DIM)[lane];
    float s = v.x*v.x + v.y*v.y + v.z*v.z + v.w*v.w;
    #pragma unroll
    for (int m = 1; m <= 32; m <<= 1) s += __shfl_xor(s, m);
    if (lane == 0) cinv[r] = 1.0f / fmaxf(sqrtf(s), 1e-12f);
}

// -------- kernel 2: barrier-free wave-per-row scan + exact select --------
// One WAVE per row, no __syncthreads, no LDS. Stream u keeping a per-lane
// online top-4 (value,col). Invariant: every dropped element <= final
// min(top4), so if min(top4) < u_thr the kept set contains ALL candidates;
// else (P~3e-4/row) take an exact full-row re-read fallback. Threshold
// inversion + eval numerics byte-identical to the R14-passing kernel.
__global__ __launch_bounds__(256) void row_kernel(
    const float* __restrict__ u, const float* __restrict__ z,
    const float* __restrict__ cb, const float* __restrict__ cinv,
    float* __restrict__ zq, float* __restrict__ emb,
    float* __restrict__ idx_out, float* __restrict__ commit_part)
{
    const int row  = blockIdx.x * 4 + (threadIdx.x >> 6);
    const int lane = threadIdx.x & 63;

    const float4* ur4 = reinterpret_cast<const float4*>(u + (size_t)row * KCODES);

    // ---- stream u row: per-lane online top-4 ----
    float tv0 = -1.f, tv1 = -1.f, tv2 = -1.f, tv3 = -1.f;
    int   tc0 = 0,    tc1 = 0,    tc2 = 0,    tc3 = 0;

    #pragma unroll 2
    for (int cc = 0; cc < 4; ++cc) {
        float4 v[4];
        #pragma unroll
        for (int j = 0; j < 4; ++j) v[j] = ur4[(cc * 4 + j) * 64 + lane];
        #pragma unroll
        for (int j = 0; j < 4; ++j) {
            const int base = ((cc * 4 + j) * 64 + lane) * 4;
            float xs[4] = {v[j].x, v[j].y, v[j].z, v[j].w};
            #pragma unroll
            for (int e = 0; e < 4; ++e) {
                float x = xs[e];
                float mn = fminf(fminf(tv0, tv1), fminf(tv2, tv3));
                if (x > mn) {
                    if      (tv0 == mn) { tv0 = x; tc0 = base + e; }
                    else if (tv1 == mn) { tv1 = x; tc1 = base + e; }
                    else if (tv2 == mn) { tv2 = x; tc2 = base + e; }
                    else                { tv3 = x; tc3 = base + e; }
                }
            }
        }
    }

    // ---- wave max + z row (1 float4/lane) ----
    float um = fmaxf(fmaxf(tv0, tv1), fmaxf(tv2, tv3));
    #pragma unroll
    for (int m = 1; m <= 32; m <<= 1) um = fmaxf(um, __shfl_xor(um, m));

    float4 zv = reinterpret_cast<const float4*>(z + (size_t)row * DIM)[lane];
    float ss = zv.x*zv.x + zv.y*zv.y + zv.z*zv.z + zv.w*zv.w;
    #pragma unroll
    for (int m = 1; m <= 32; m <<= 1) ss += __shfl_xor(ss, m);
    const float zinv = 1.0f / fmaxf(sqrtf(ss), 1e-12f);
    float4 zn;
    zn.x = zv.x*zinv; zn.y = zv.y*zinv; zn.z = zv.z*zinv; zn.w = zv.w*zinv;

    // ---- invert threshold into u-space (identical formula to R14) ----
    const float gmax  = -logf(-logf(um + 1e-10f) + 1e-10f);
    const float y_thr = expf(-(gmax - 2.06f)) - 1e-10f;
    float u_thr = expf(-y_thr) - 1e-10f;
    u_thr = u_thr - fabsf(u_thr) * 2e-6f - 1e-12f;   // few-ulp safety shrink

    float best = -3.0e38f;
    int   bi   = 1 << 30;

    auto evalc = [&](float uu, int col) {
        float4 cv = reinterpret_cast<const float4*>(cb + (size_t)col * DIM)[lane];
        float civ = cinv[col];
        float d = zn.x*(cv.x*civ) + zn.y*(cv.y*civ) + zn.z*(cv.z*civ) + zn.w*(cv.w*civ);
        #pragma unroll
        for (int m = 1; m <= 32; m <<= 1) d += __shfl_xor(d, m);
        float y1 = -logf(uu + 1e-10f);
        float g  = -logf(y1 + 1e-10f);
        float val = (d - 1.0f) + g;
        if (val > best || (val == best && col < bi)) { best = val; bi = col; }
    };

    // ---- overflow check: lane's 4 kept all >= thr -> may have dropped one ----
    const float m4 = fminf(fminf(tv0, tv1), fminf(tv2, tv3));
    if (__ballot(m4 >= u_thr)) {
        // exact fallback: re-read row, eval every element >= thr (rare)
        for (int c = 0; c < 16; ++c) {
            float4 vv = ur4[c * 64 + lane];
            float xs[4] = {vv.x, vv.y, vv.z, vv.w};
            #pragma unroll
            for (int e = 0; e < 4; ++e) {
                unsigned long long mm = __ballot(xs[e] >= u_thr);
                while (mm) {
                    int src = __ffsll(mm) - 1;
                    mm &= mm - 1;
                    float uu = __shfl(xs[e], src);
                    int  col = (c * 64 + src) * 4 + e;
                    evalc(uu, col);
                }
            }
        }
    } else {
        // main path: enumerate per-lane top-4 hits via ballot+shfl
        float tvs[4] = {tv0, tv1, tv2, tv3};
        int   tcs[4] = {tc0, tc1, tc2, tc3};
        #pragma unroll
        for (int j = 0; j < 4; ++j) {
            unsigned long long mm = __ballot(tvs[j] >= u_thr);
            while (mm) {
                int src = __ffsll(mm) - 1;
                mm &= mm - 1;
                float uu = __shfl(tvs[j], src);
                int  col = __shfl(tcs[j], src);
                evalc(uu, col);
            }
        }
    }

    // ---- winner gather + outputs (wave-private) ----
    float4 cw = reinterpret_cast<const float4*>(cb + (size_t)bi * DIM)[lane];
    reinterpret_cast<float4*>(zq  + (size_t)row * DIM)[lane] = cw;
    reinterpret_cast<float4*>(emb + (size_t)row * DIM)[lane] = cw;
    float dx = cw.x - zv.x, dy = cw.y - zv.y, dz = cw.z - zv.z, dw = cw.w - zv.w;
    float s2 = dx*dx + dy*dy + dz*dz + dw*dw;
    #pragma unroll
    for (int m = 1; m <= 32; m <<= 1) s2 += __shfl_xor(s2, m);
    if (lane == 0) {
        idx_out[row]     = (float)bi;
        commit_part[row] = s2;
    }
}

// -------- kernel 3: parallel commit reduction (16 blocks, float4 loads) --------
__global__ __launch_bounds__(256) void commit_reduce_kernel(
    const float* __restrict__ commit_part, float* __restrict__ commit_acc)
{
    __shared__ float red[256];
    const int t = threadIdx.x;
    float4 v = reinterpret_cast<const float4*>(commit_part)[blockIdx.x * 256 + t];
    red[t] = v.x + v.y + v.z + v.w;
    __syncthreads();
    for (int w = 128; w > 0; w >>= 1) { if (t < w) red[t] += red[t + w]; __syncthreads(); }
    if (t == 0) atomicAdd(commit_acc, red[0]);
}

// -------- kernel 4: scalars (commitment, entropy bonus, perplexity, entropy) --------
__global__ __launch_bounds__(256) void scalars_kernel(
    const float* __restrict__ commit_acc, const float* __restrict__ usage,
    const int* __restrict__ step_ptr, float* __restrict__ out4)
{
    __shared__ float red[256];
    int t = threadIdx.x;

    float us = 0.f;
    for (int i = t; i < KCODES; i += 256) us += usage[i];
    red[t] = us; __syncthreads();
    for (int w = 128; w > 0; w >>= 1) { if (t < w) red[t] += red[t + w]; __syncthreads(); }
    float usage_sum = red[0];
    __syncthreads();

    float e = 0.f;
    for (int i = t; i < KCODES; i += 256) {
        float p = (usage_sum > 0.f) ? usage[i] / (usage_sum + 1e-10f) : (1.0f / KCODES);
        e += p * logf(p + 1e-10f);
    }
    red[t] = e; __syncthreads();
    for (int w = 128; w > 0; w >>= 1) { if (t < w) red[t] += red[t + w]; __syncthreads(); }

    if (t == 0) {
        float entropy = -red[0];
        int step_after = step_ptr[0] + 1;
        float bonus_w = 0.05f * (1.0f - (float)step_after / 20000.0f);
        float eb = (step_after < 20000) ? (-bonus_w * entropy) : 0.0f;
        out4[0] = 0.5f * commit_acc[0] / 4194304.0f;
        out4[1] = eb;
        out4[2] = expf(entropy);
        out4[3] = entropy;
    }
}

extern "C" void kernel_launch(void* const* d_in, const int* in_sizes, int n_in,
                              void* d_out, int out_size, void* d_ws, size_t ws_size,
                              hipStream_t stream)
{
    const float* z     = (const float*)d_in[0];   // [16,1024,256]
    const float* u     = (const float*)d_in[1];   // [16,1024,4096]
    const float* cb    = (const float*)d_in[2];   // [4096,256]
    const float* usage = (const float*)d_in[3];   // [4096]
    const int*   step  = (const int*)d_in[4];     // scalar

    float* out  = (float*)d_out;
    float* zq   = out;                 // 4194304
    float* emb  = out + 4194304;       // 4194304
    float* idxo = out + 8388608;       // 16384
    float* scal = out + 8404992;       // 4

    float* ws          = (float*)d_ws;
    float* cinv        = ws;           // 4096
    float* commit_part = ws + 4096;    // 16384
    float* commit_acc  = ws + 20480;   // 1

    hipMemsetAsync(commit_acc, 0, sizeof(float), stream);
    hipLaunchKernelGGL(cinv_kernel, dim3(1024), dim3(256), 0, stream, cb, cinv);
    hipLaunchKernelGGL(row_kernel, dim3(N_ROWS / 4), dim3(256), 0, stream,
                       u, z, cb, cinv, zq, emb, idxo, commit_part);
    hipLaunchKernelGGL(commit_reduce_kernel, dim3(16), dim3(256), 0, stream,
                       commit_part, commit_acc);
    hipLaunchKernelGGL(scalars_kernel, dim3(1), dim3(256), 0, stream,
                       commit_acc, usage, step, scal);
}